// Round 4
// baseline (312.292 us; speedup 1.0000x reference)
//
#include <hip/hip_runtime.h>
#include <stdint.h>

#define NH 8
#define D 8
#define HH 48
#define WW 48
#define NQ (HH*WW)            // 2304
#define BB 2
#define NBH (BB*NH)           // 16
#define PACK (NBH*NQ*D)       // 294912 floats (Q)
#define KVPACK (NBH*NQ*2*D)   // 589824 floats (interleaved K|V)
#define NQG (NBH*NQ)          // 36864 total queries
#define PSTRIDE (NQG*9)       // 331776 floats per partial set

// ws layout (floats): [0,PACK) Q | [PACK, PACK+KVPACK) KV | then P[2][NQG][9]
#define WS_P (PACK + KVPACK)  // 884736

// ---------------------------------------------------------------------------
// Kernel 1: repack fp32 [B,H,W,192] -> Q [bh][n][8] (pre-scaled by 8^-0.5)
//           and interleaved KV [bh][n][16] (k0..k7, v0..v7)
// ---------------------------------------------------------------------------
__global__ __launch_bounds__(256) void repack_kernel(const float* __restrict__ in,
                                                     float* __restrict__ ws) {
    int tid = blockIdx.x * blockDim.x + threadIdx.x;   // [0, PACK+KVPACK)
    if (tid < PACK) {
        int d = tid & 7;
        int n2 = tid >> 3;
        int n = n2 % NQ;
        int bh = n2 / NQ;
        int h = bh & 7;
        ws[tid] = in[((size_t)(bh >> 3) * NQ + n) * 192 + h * 8 + d]
                  * 0.35355339059327373f;   // 8^-0.5
    } else {
        int r = tid - PACK;
        int j = r & 15;
        int n2 = r >> 4;
        int n = n2 % NQ;
        int bh = n2 / NQ;
        int h = bh & 7;
        int c = (j < 8) ? (64 + h * 8 + j) : (128 + h * 8 + (j - 8));
        ws[tid] = in[((size_t)(bh >> 3) * NQ + n) * 192 + c];
    }
}

// ---------------------------------------------------------------------------
// Kernel 2: attention partials. Lane = query (64 queries/wave, broadcast KV).
// logit[q=(y,x), k=(y2,x2)] = q.k + q.rel_w[x2-x+47] + q.rel_h[y2-y+47]
// qw[48] precomputed per lane; qh once per key row. Fixed-shift softmax
// (M0=12) so partials merge by plain addition.
// grid: 16 bh x 36 qtiles x 2 key-halves; block 256 = 4 waves x 6 key-rows.
// ---------------------------------------------------------------------------
__global__ __launch_bounds__(256) void attn_kernel(const float* __restrict__ Qf,
                                                   const float* __restrict__ KV,
                                                   const float* __restrict__ relw,
                                                   const float* __restrict__ relh,
                                                   float* __restrict__ P) {
    __shared__ float red[4][64][9];

    const int bx = blockIdx.x;
    const int bh = bx / 72;
    const int rem = bx % 72;
    const int qt = rem >> 1;
    const int half = rem & 1;
    const int lane = threadIdx.x & 63;
    const int wv = threadIdx.x >> 6;
    const int n = qt * 64 + lane;          // query index within (b,h)
    const int y = n / WW;
    const int x = n - y * WW;

    const float4* qp = (const float4*)(Qf + ((size_t)bh * NQ + n) * D);
    const float4 qa = qp[0];
    const float4 qb = qp[1];

    // qw[x2] = q . rel_w[x2 - x + 47]   (fully unrolled -> constant indices)
    float qw[48];
#pragma unroll
    for (int x2 = 0; x2 < 48; ++x2) {
        const float* rw = relw + (x2 - x + 47) * 8;
        float4 ta = *(const float4*)rw;
        float4 tb = *(const float4*)(rw + 4);
        qw[x2] = qa.x * ta.x + qa.y * ta.y + qa.z * ta.z + qa.w * ta.w
               + qb.x * tb.x + qb.y * tb.y + qb.z * tb.z + qb.w * tb.w;
    }

    float l = 0.0f;
    float a0 = 0, a1 = 0, a2 = 0, a3 = 0, a4 = 0, a5 = 0, a6 = 0, a7 = 0;

    const int r0 = half * 24 + wv * 6;     // this wave's 6 key rows
#pragma unroll 1
    for (int rr = 0; rr < 6; ++rr) {
        int r = r0 + rr;
        const float* rh = relh + (r - y + 47) * 8;
        float4 ha = *(const float4*)rh;
        float4 hb = *(const float4*)(rh + 4);
        float qh = qa.x * ha.x + qa.y * ha.y + qa.z * ha.z + qa.w * ha.w
                 + qb.x * hb.x + qb.y * hb.y + qb.z * hb.z + qb.w * hb.w;

        const float* kvr = KV + ((size_t)(bh * NQ + r * WW) << 4); // wave-uniform
#pragma unroll
        for (int x2 = 0; x2 < 48; ++x2) {
            const float4* kv = (const float4*)(kvr + (x2 << 4));
            float4 k0 = kv[0];
            float4 k1 = kv[1];
            float4 v0 = kv[2];
            float4 v1 = kv[3];
            float dt = qh + qw[x2];
            dt = fmaf(qa.x, k0.x, dt); dt = fmaf(qa.y, k0.y, dt);
            dt = fmaf(qa.z, k0.z, dt); dt = fmaf(qa.w, k0.w, dt);
            dt = fmaf(qb.x, k1.x, dt); dt = fmaf(qb.y, k1.y, dt);
            dt = fmaf(qb.z, k1.z, dt); dt = fmaf(qb.w, k1.w, dt);
            float p = __expf(dt - 12.0f);   // fixed-shift softmax
            l += p;
            a0 = fmaf(p, v0.x, a0); a1 = fmaf(p, v0.y, a1);
            a2 = fmaf(p, v0.z, a2); a3 = fmaf(p, v0.w, a3);
            a4 = fmaf(p, v1.x, a4); a5 = fmaf(p, v1.y, a5);
            a6 = fmaf(p, v1.z, a6); a7 = fmaf(p, v1.w, a7);
        }
    }

    // in-block merge of the 4 waves' partials
    red[wv][lane][0] = l;
    red[wv][lane][1] = a0; red[wv][lane][2] = a1;
    red[wv][lane][3] = a2; red[wv][lane][4] = a3;
    red[wv][lane][5] = a4; red[wv][lane][6] = a5;
    red[wv][lane][7] = a6; red[wv][lane][8] = a7;
    __syncthreads();

    for (int i = threadIdx.x; i < 576; i += 256) {
        int q = i / 9;
        int j = i - q * 9;
        float s = red[0][q][j] + red[1][q][j] + red[2][q][j] + red[3][q][j];
        size_t qg = (size_t)bh * NQ + qt * 64 + q;
        P[(size_t)half * PSTRIDE + qg * 9 + j] = s;
    }
}

// ---------------------------------------------------------------------------
// Kernel 3: merge the 2 key-half partials, normalize, write output
// out[b][n][h*8+j]
// ---------------------------------------------------------------------------
__global__ __launch_bounds__(256) void merge_kernel(const float* __restrict__ P,
                                                    float* __restrict__ out) {
    int t = blockIdx.x * blockDim.x + threadIdx.x;   // [0, NQG)
    const float* p0 = P + (size_t)t * 9;
    const float* p1 = p0 + PSTRIDE;
    float inv = 1.0f / (p0[0] + p1[0]);
    int bh = t / NQ;
    int n = t - bh * NQ;
    int b = bh >> 3, h = bh & 7;
    float* op = out + ((size_t)(b * NQ + n) * 64 + h * 8);
    float4 o0, o1;
    o0.x = (p0[1] + p1[1]) * inv; o0.y = (p0[2] + p1[2]) * inv;
    o0.z = (p0[3] + p1[3]) * inv; o0.w = (p0[4] + p1[4]) * inv;
    o1.x = (p0[5] + p1[5]) * inv; o1.y = (p0[6] + p1[6]) * inv;
    o1.z = (p0[7] + p1[7]) * inv; o1.w = (p0[8] + p1[8]) * inv;
    ((float4*)op)[0] = o0;
    ((float4*)op)[1] = o1;
}

extern "C" void kernel_launch(void* const* d_in, const int* in_sizes, int n_in,
                              void* d_out, int out_size, void* d_ws, size_t ws_size,
                              hipStream_t stream) {
    const float* in   = (const float*)d_in[0];
    const float* relw = (const float*)d_in[1];
    const float* relh = (const float*)d_in[2];
    float* ws  = (float*)d_ws;
    float* out = (float*)d_out;

    float* Qf = ws;
    float* KV = ws + PACK;
    float* P  = ws + WS_P;

    repack_kernel<<<(PACK + KVPACK) / 256, 256, 0, stream>>>(in, ws);
    attn_kernel<<<NBH * 72, 256, 0, stream>>>(Qf, KV, relw, relh, P);
    merge_kernel<<<NQG / 256, 256, 0, stream>>>(P, out);
}

// Round 5
// 153.481 us; speedup vs baseline: 2.0347x; 2.0347x over previous
//
#include <hip/hip_runtime.h>
#include <stdint.h>

#define NH 8
#define D 8
#define HH 48
#define WW 48
#define NQ (HH*WW)          // 2304
#define BB 2
#define NBH (BB*NH)         // 16
#define NQG (NBH*NQ)        // 36864 queries total
#define NGT 576             // wave-tiles of 64 queries (16 bh * 9 qt * 4 wv)
#define SCL 0.51011868f     // 8^-0.5 * log2(e)  (folded so softmax = exp2)
#define SHIFT 17.312340491f // 12 * log2(e)      (fixed-shift softmax)

// ---------------------------------------------------------------------------
// attn: lane = query (256 distinct queries / block, 4 waves).
// Block stages its key-chunk (ROWS rows * 48 keys * 16 floats) into LDS once;
// all waves consume via ds_read_b128 broadcast (conflict-free).
// logit = q.k + q.rel_w[x2-x+47] + q.rel_h[y2-y+47]; p = exp2(logit' - SHIFT)
// Partials (l, acc[8]) written per wave-tile slab, coalesced [j][64lane].
// ---------------------------------------------------------------------------
template<int ROWS>
__global__ __launch_bounds__(256) void attn_kernel(const float* __restrict__ in,
                                                   const float* __restrict__ relw,
                                                   const float* __restrict__ relh,
                                                   float* __restrict__ P) {
    extern __shared__ float4 kvbuf[];
    const float* kvf = (const float*)kvbuf;
    constexpr int NCH = 48 / ROWS;          // number of key chunks

    const int bx = blockIdx.x;
    const int bh = bx / (9 * NCH);
    const int rem = bx % (9 * NCH);
    const int qt = rem / NCH;
    const int kc = rem % NCH;
    const int tid = threadIdx.x;
    const int lane = tid & 63;
    const int wv = tid >> 6;
    const int b = bh >> 3, h = bh & 7;

    const float4* inp4 = (const float4*)in;   // 48 float4 per pixel row of C=192
    const int m0 = kc * (ROWS * 48);          // first key index in this chunk

    // ---- stage KV chunk into LDS: key -> [k0..k7, v0..v7] ----
    const int items = ROWS * 48 * 4;          // float4 count
    for (int i = tid; i < items; i += 256) {
        int key = i >> 2, p = i & 3;
        int c4 = 16 + ((p >> 1) << 4) + h * 2 + (p & 1);  // K at c=64+, V at c=128+
        kvbuf[(key << 2) + p] = inp4[(size_t)(b * NQ + m0 + key) * 48 + c4];
    }

    // ---- per-lane query (scaled by 8^-0.5 * log2e) ----
    const int n = qt * 256 + wv * 64 + lane;
    const int y = n / WW, x = n - y * WW;
    float4 qa = inp4[(size_t)(b * NQ + n) * 48 + h * 2];
    float4 qb = inp4[(size_t)(b * NQ + n) * 48 + h * 2 + 1];
    qa.x *= SCL; qa.y *= SCL; qa.z *= SCL; qa.w *= SCL;
    qb.x *= SCL; qb.y *= SCL; qb.z *= SCL; qb.w *= SCL;

    // qw[x2] = q . rel_w[x2 - x + 47]
    float qw[48];
#pragma unroll
    for (int x2 = 0; x2 < 48; ++x2) {
        const float* rw = relw + (x2 - x + 47) * 8;
        float4 ta = *(const float4*)rw;
        float4 tb = *(const float4*)(rw + 4);
        qw[x2] = qa.x * ta.x + qa.y * ta.y + qa.z * ta.z + qa.w * ta.w
               + qb.x * tb.x + qb.y * tb.y + qb.z * tb.z + qb.w * tb.w;
    }

    __syncthreads();

    float l = 0.0f;
    float a0 = 0, a1 = 0, a2 = 0, a3 = 0, a4 = 0, a5 = 0, a6 = 0, a7 = 0;

#pragma unroll 1
    for (int rr = 0; rr < ROWS; ++rr) {
        const int r = kc * ROWS + rr;       // key row y2
        const float* rh = relh + (r - y + 47) * 8;
        float4 ha = *(const float4*)rh;
        float4 hb = *(const float4*)(rh + 4);
        float qh = qa.x * ha.x + qa.y * ha.y + qa.z * ha.z + qa.w * ha.w
                 + qb.x * hb.x + qb.y * hb.y + qb.z * hb.z + qb.w * hb.w
                 - SHIFT;

        const float* kvr = kvf + (size_t)rr * (48 * 16);
#pragma unroll
        for (int x2 = 0; x2 < 48; ++x2) {
            float4 k0 = *(const float4*)(kvr + (x2 << 4));
            float4 k1 = *(const float4*)(kvr + (x2 << 4) + 4);
            float4 v0 = *(const float4*)(kvr + (x2 << 4) + 8);
            float4 v1 = *(const float4*)(kvr + (x2 << 4) + 12);
            float dt = qh + qw[x2];
            dt = fmaf(qa.x, k0.x, dt); dt = fmaf(qa.y, k0.y, dt);
            dt = fmaf(qa.z, k0.z, dt); dt = fmaf(qa.w, k0.w, dt);
            dt = fmaf(qb.x, k1.x, dt); dt = fmaf(qb.y, k1.y, dt);
            dt = fmaf(qb.z, k1.z, dt); dt = fmaf(qb.w, k1.w, dt);
            float p = __builtin_amdgcn_exp2f(dt);
            l += p;
            a0 = fmaf(p, v0.x, a0); a1 = fmaf(p, v0.y, a1);
            a2 = fmaf(p, v0.z, a2); a3 = fmaf(p, v0.w, a3);
            a4 = fmaf(p, v1.x, a4); a5 = fmaf(p, v1.y, a5);
            a6 = fmaf(p, v1.z, a6); a7 = fmaf(p, v1.w, a7);
        }
    }

    // ---- write partials, coalesced: slab = (kc*NGT + g), layout [9][64] ----
    const int g = (bh * 9 + qt) * 4 + wv;   // wave-tile id [0, 576)
    float* pb = P + (size_t)(kc * NGT + g) * 576;
    pb[0 * 64 + lane] = l;
    pb[1 * 64 + lane] = a0; pb[2 * 64 + lane] = a1;
    pb[3 * 64 + lane] = a2; pb[4 * 64 + lane] = a3;
    pb[5 * 64 + lane] = a4; pb[6 * 64 + lane] = a5;
    pb[7 * 64 + lane] = a6; pb[8 * 64 + lane] = a7;
}

// ---------------------------------------------------------------------------
// merge: sum nch partials per query, normalize, write out[b][n][h*8+j]
// ---------------------------------------------------------------------------
__global__ __launch_bounds__(256) void merge_kernel(const float* __restrict__ P,
                                                    float* __restrict__ out,
                                                    int nch) {
    const int t = blockIdx.x * blockDim.x + threadIdx.x;  // [0, NQG)
    const int g = t >> 6, lane = t & 63;
    float s[9];
#pragma unroll
    for (int j = 0; j < 9; ++j) s[j] = 0.0f;
    for (int c = 0; c < nch; ++c) {
        const float* pb = P + (size_t)(c * NGT + g) * 576;
#pragma unroll
        for (int j = 0; j < 9; ++j) s[j] += pb[j * 64 + lane];
    }
    float inv = 1.0f / s[0];
    const int bh = g / 36;
    const int r = g % 36;
    const int n = (r >> 2) * 256 + (r & 3) * 64 + lane;
    const int b = bh >> 3, h = bh & 7;
    float* op = out + ((size_t)(b * NQ + n) * 64 + h * 8);
    float4 o0 = make_float4(s[1] * inv, s[2] * inv, s[3] * inv, s[4] * inv);
    float4 o1 = make_float4(s[5] * inv, s[6] * inv, s[7] * inv, s[8] * inv);
    ((float4*)op)[0] = o0;
    ((float4*)op)[1] = o1;
}

extern "C" void kernel_launch(void* const* d_in, const int* in_sizes, int n_in,
                              void* d_out, int out_size, void* d_ws, size_t ws_size,
                              hipStream_t stream) {
    const float* in   = (const float*)d_in[0];
    const float* relw = (const float*)d_in[1];
    const float* relh = (const float*)d_in[2];
    float* P   = (float*)d_ws;
    float* out = (float*)d_out;

    // P needs nch * 576 slabs * 576 floats * 4 B; pick split by ws budget
    const size_t need8 = (size_t)8 * NGT * 576 * 4;
    if (ws_size >= need8) {
        attn_kernel<6><<<NBH * 9 * 8, 256, 6 * 48 * 64, stream>>>(in, relw, relh, P);
        merge_kernel<<<NQG / 256, 256, 0, stream>>>(P, out, 8);
    } else {
        attn_kernel<12><<<NBH * 9 * 4, 256, 12 * 48 * 64, stream>>>(in, relw, relh, P);
        merge_kernel<<<NQG / 256, 256, 0, stream>>>(P, out, 4);
    }
}